// Round 5
// baseline (355.824 us; speedup 1.0000x reference)
//
#include <hip/hip_runtime.h>

#define BB 8
#define NN 1024
#define DIN 64
#define DOUT 64
#define EMB 16
#define DPC 16
#define GRID 512

typedef __attribute__((ext_vector_type(8))) short bf16x8;
typedef __attribute__((ext_vector_type(4))) float f32x4;

__device__ inline unsigned short f2bf(float f) {
    unsigned u = __float_as_uint(f);
    u += 0x7fffu + ((u >> 16) & 1u);      // RNE (finite only)
    return (unsigned short)(u >> 16);
}

// device-scope grid barrier; counter must be zeroed before launch.
// Co-residency guaranteed: 512 blocks, 34KB LDS -> 2 blocks/CU (cap 4 by LDS).
__device__ inline void gridbar(int* bar, int tid) {
    __syncthreads();
    if (tid == 0) {
        __threadfence();   // release: wbL2 -> my writes visible device-wide
        __hip_atomic_fetch_add(bar, 1, __ATOMIC_ACQ_REL, __HIP_MEMORY_SCOPE_AGENT);
        while (__hip_atomic_load(bar, __ATOMIC_ACQUIRE, __HIP_MEMORY_SCOPE_AGENT) < GRID)
            __builtin_amdgcn_s_sleep(2);
    }
    __syncthreads();
    __threadfence();       // acquire: invL1/L2 -> see others' writes
}

#define ASTR 72
#define BSTR 72

// C[16m x 64d] = A[16m x 1024k] * B^T[64d x 1024k], K-step 64, reg prefetch.
__device__ inline void gemm_tile(const unsigned short* __restrict__ Arow,
                                 const unsigned short* __restrict__ Brow,
                                 unsigned short* A_l, unsigned short* B_l,
                                 int tid, f32x4& acc) {
    const int lane = tid & 63, wave = tid >> 6;
    const int q = lane >> 4, r = lane & 15;
    const int brow_ = tid >> 2, bch = (tid & 3) * 2;
    const int arow_ = tid >> 3, ach = tid & 7;

    uint4 pb0 = *(const uint4*)&Brow[(size_t)brow_*NN + (bch+0)*8];
    uint4 pb1 = *(const uint4*)&Brow[(size_t)brow_*NN + (bch+1)*8];
    uint4 pa0;
    if (tid < 128) pa0 = *(const uint4*)&Arow[(size_t)arow_*NN + ach*8];

    for (int kk = 0; kk < 16; ++kk) {
        __syncthreads();
        *(uint4*)&B_l[brow_*BSTR + (bch+0)*8] = pb0;
        *(uint4*)&B_l[brow_*BSTR + (bch+1)*8] = pb1;
        if (tid < 128) *(uint4*)&A_l[arow_*ASTR + ach*8] = pa0;
        __syncthreads();
        if (kk < 15) {
            int c1 = (kk + 1) * 64;
            pb0 = *(const uint4*)&Brow[(size_t)brow_*NN + c1 + (bch+0)*8];
            pb1 = *(const uint4*)&Brow[(size_t)brow_*NN + c1 + (bch+1)*8];
            if (tid < 128) pa0 = *(const uint4*)&Arow[(size_t)arow_*NN + c1 + ach*8];
        }
        bf16x8 a0 = *(const bf16x8*)&A_l[r*ASTR + q*8];
        bf16x8 b0 = *(const bf16x8*)&B_l[(wave*16 + r)*BSTR + q*8];
        acc = __builtin_amdgcn_mfma_f32_16x16x32_bf16(a0, b0, acc, 0, 0, 0);
        bf16x8 a1 = *(const bf16x8*)&A_l[r*ASTR + 32 + q*8];
        bf16x8 b1 = *(const bf16x8*)&B_l[(wave*16 + r)*BSTR + 32 + q*8];
        acc = __builtin_amdgcn_mfma_f32_16x16x32_bf16(a1, b1, acc, 0, 0, 0);
    }
}

// =======================================================================
// One persistent kernel, 512 blocks x 256 threads, 4 phases + 3 grid bars.
// =======================================================================
__global__ __launch_bounds__(256, 2) void k_mega(
        const float* __restrict__ E,  const float* __restrict__ pa,
        const float* __restrict__ x,  const float* __restrict__ wp,
        const float* __restrict__ bp,
        unsigned short* __restrict__ sim_bf, unsigned short* __restrict__ Sub,
        unsigned short* __restrict__ xzT,    unsigned short* __restrict__ W2,
        unsigned short* __restrict__ sxT,    float* __restrict__ sx,
        float* __restrict__ y,               float* __restrict__ out,
        int* __restrict__ bars) {
    __shared__ __align__(16) char smem[34816];
    const int bid = blockIdx.x, tid = threadIdx.x;
    const int lane = tid & 63, wave = tid >> 6;

    // ---------------- P1a: z3 — Z + Sub + xzT (16 c-rows per block) ----------------
    {
        const int b = bid >> 6, c0 = (bid & 63) * 16;
        float* pa_l  = (float*)smem;                 // 512*16 f = 32 KB (reused as xl)
        float* zpart = (float*)(smem + 32768);       // 16*16 f = 1 KB
        float* invZ  = (float*)(smem + 33792);       // 16 f

        const int cs = tid & 15, jq = tid >> 4;      // row, j-group (32 j each)
        float myc[DPC];
        #pragma unroll
        for (int p4 = 0; p4 < 4; ++p4) {
            float4 t = *(const float4*)&pa[((size_t)b*NN + c0 + cs)*DPC + p4*4];
            myc[p4*4+0] = t.x; myc[p4*4+1] = t.y; myc[p4*4+2] = t.z; myc[p4*4+3] = t.w;
        }

        float part = 0.0f;
        for (int h = 0; h < 2; ++h) {
            __syncthreads();
            for (int i = tid; i < 2048; i += 256)
                ((float4*)pa_l)[i] = ((const float4*)(pa + ((size_t)b*NN + h*512)*DPC))[i];
            __syncthreads();
            unsigned short* subrow = Sub + ((size_t)b*NN + c0 + cs)*NN + h*512 + jq*32;
            for (int j8 = 0; j8 < 8; ++j8) {
                float e[4];
                #pragma unroll
                for (int t = 0; t < 4; ++t) {
                    int jj = jq*32 + j8*4 + t;
                    float s = 0.0f;
                    #pragma unroll
                    for (int p4 = 0; p4 < 4; ++p4) {
                        float4 qv = *(const float4*)&pa_l[jj*DPC + p4*4];
                        s += fabsf(myc[p4*4+0]-qv.x) + fabsf(myc[p4*4+1]-qv.y)
                           + fabsf(myc[p4*4+2]-qv.z) + fabsf(myc[p4*4+3]-qv.w);
                    }
                    e[t] = __expf(-s);
                }
                part += e[0] + e[1] + e[2] + e[3];
                *(ushort4*)&subrow[j8*4] =
                    make_ushort4(f2bf(e[0]), f2bf(e[1]), f2bf(e[2]), f2bf(e[3]));
            }
        }
        zpart[jq*16 + cs] = part;
        __syncthreads();
        float* xl = pa_l;                            // reuse: xl[16][65]
        #pragma unroll
        for (int i = 0; i < 4; ++i) {
            int l = i*256 + tid, d = l & 63, c = l >> 6;
            xl[c*65 + d] = x[((size_t)b*NN + c0 + c)*DIN + d];
        }
        if (tid < 16) {
            float z = 0.f;
            #pragma unroll
            for (int q2 = 0; q2 < 16; ++q2) z += zpart[q2*16 + tid];
            invZ[tid] = 1.0f / z;
        }
        __syncthreads();
        #pragma unroll
        for (int i = 0; i < 4; ++i) {
            int l = i*256 + tid, c = l & 15, d = l >> 4;
            xzT[((size_t)b*DIN + d)*NN + c0 + c] = f2bf(xl[c*65 + d] * invZ[c]);
        }
    }

    // ---------------- P1b: wgen — W2 (16 n-rows x 1024 kio per block) ----------------
    {
        const int n0 = (bid >> 3) * 16;
        const int kio0 = (bid & 7) * 1024 + tid * 4;
        __syncthreads();
        float* El = (float*)smem;                    // 16*16 f
        if (tid < 64) ((float4*)El)[tid] = ((const float4*)&E[n0*EMB])[tid];
        float4 wq[EMB];
        #pragma unroll
        for (int d = 0; d < EMB; ++d)
            wq[d] = *(const float4*)&wp[d*8192 + kio0];
        __syncthreads();
        for (int n = 0; n < 16; ++n) {
            float4 a = make_float4(0.f, 0.f, 0.f, 0.f);
            #pragma unroll
            for (int d = 0; d < EMB; ++d) {
                float e = El[n*EMB + d];
                a.x += e*wq[d].x; a.y += e*wq[d].y; a.z += e*wq[d].z; a.w += e*wq[d].w;
            }
            *(ushort4*)&W2[(size_t)(n0 + n)*8192 + kio0] =
                make_ushort4(f2bf(a.x), f2bf(a.y), f2bf(a.z), f2bf(a.w));
        }
    }

    // ---------------- P1c: sim — 2 rows per block ----------------
    {
        float* redw = (float*)smem;                  // 4 f
        for (int s2 = 0; s2 < 2; ++s2) {
            const int row = bid*2 + s2;
            __syncthreads();                         // protect redw reuse
            float4 ei0 = *(const float4*)&E[row*EMB + 0];
            float4 ei1 = *(const float4*)&E[row*EMB + 4];
            float4 ei2 = *(const float4*)&E[row*EMB + 8];
            float4 ei3 = *(const float4*)&E[row*EMB + 12];

            float rv[4], tmax = -1e30f;
            #pragma unroll
            for (int k = 0; k < 4; ++k) {
                int j = tid + k*256;
                float4 a0 = *(const float4*)&E[j*EMB + 0];
                float4 a1 = *(const float4*)&E[j*EMB + 4];
                float4 a2 = *(const float4*)&E[j*EMB + 8];
                float4 a3 = *(const float4*)&E[j*EMB + 12];
                float s = ei0.x*a0.x + ei0.y*a0.y + ei0.z*a0.z + ei0.w*a0.w
                        + ei1.x*a1.x + ei1.y*a1.y + ei1.z*a1.z + ei1.w*a1.w
                        + ei2.x*a2.x + ei2.y*a2.y + ei2.z*a2.z + ei2.w*a2.w
                        + ei3.x*a3.x + ei3.y*a3.y + ei3.z*a3.z + ei3.w*a3.w;
                s = fmaxf(s, 0.0f);
                rv[k] = s; tmax = fmaxf(tmax, s);
            }
            #pragma unroll
            for (int off = 32; off > 0; off >>= 1) tmax = fmaxf(tmax, __shfl_xor(tmax, off));
            if (lane == 0) redw[wave] = tmax;
            __syncthreads();
            float rmax = fmaxf(fmaxf(redw[0], redw[1]), fmaxf(redw[2], redw[3]));
            __syncthreads();

            float ev[4], tsum = 0.f;
            #pragma unroll
            for (int k = 0; k < 4; ++k) { ev[k] = __expf(rv[k] - rmax); tsum += ev[k]; }
            #pragma unroll
            for (int off = 32; off > 0; off >>= 1) tsum += __shfl_xor(tsum, off);
            if (lane == 0) redw[wave] = tsum;
            __syncthreads();
            float inv = 1.0f / (redw[0] + redw[1] + redw[2] + redw[3]);
            #pragma unroll
            for (int k = 0; k < 4; ++k)
                sim_bf[(size_t)row*NN + tid + k*256] = f2bf(ev[k] * inv);
        }
    }

    gridbar(&bars[0], tid);

    // ---------------- P2: sx = Sub @ xz (one 16x64 tile per block) ----------------
    {
        const int b = bid >> 6, m0 = (bid & 63) * 16;
        unsigned short* A_l = (unsigned short*)smem;             // 2304 B
        unsigned short* B_l = (unsigned short*)(smem + 2304);    // 9216 B
        f32x4 acc = {0.f, 0.f, 0.f, 0.f};
        gemm_tile(Sub + ((size_t)b*NN + m0)*NN, xzT + (size_t)b*DIN*NN, A_l, B_l, tid, acc);
        const int q = lane >> 4, r = lane & 15;
        const int d = wave*16 + r, mrow = m0 + q*4;
        #pragma unroll
        for (int reg = 0; reg < 4; ++reg)
            sx[((size_t)b*NN + mrow + reg)*DIN + d] = acc[reg];
        *(ushort4*)&sxT[((size_t)b*DIN + d)*NN + mrow] =
            make_ushort4(f2bf(acc[0]), f2bf(acc[1]), f2bf(acc[2]), f2bf(acc[3]));
    }

    gridbar(&bars[1], tid);

    // ---------------- P3: y = sim @ sx ----------------
    {
        const int b = bid >> 6, m0 = (bid & 63) * 16;
        unsigned short* A_l = (unsigned short*)smem;
        unsigned short* B_l = (unsigned short*)(smem + 2304);
        f32x4 acc = {0.f, 0.f, 0.f, 0.f};
        gemm_tile(sim_bf + (size_t)m0*NN, sxT + (size_t)b*DIN*NN, A_l, B_l, tid, acc);
        const int q = lane >> 4, r = lane & 15;
        const int d = wave*16 + r, mrow = m0 + q*4;
        #pragma unroll
        for (int reg = 0; reg < 4; ++reg)
            y[((size_t)b*NN + mrow + reg)*DIN + d] = acc[reg];
    }

    gridbar(&bars[2], tid);

    // ---------------- P4: out — 2 nodes per block ----------------
    {
        uint4*  W2l4 = (uint4*)smem;                 // 16 KB
        float*  vl   = (float*)(smem + 16384);       // 4 KB
        float*  El2  = (float*)(smem + 20480);       // 64 B
        for (int s2 = 0; s2 < 2; ++s2) {
            const int n = bid*2 + s2;
            __syncthreads();
            if (tid < EMB) El2[tid] = E[n*EMB + tid];
            {
                const uint4* src = (const uint4*)(W2 + (size_t)n * 8192);
                #pragma unroll
                for (int r2 = 0; r2 < 4; ++r2) W2l4[tid + r2*256] = src[tid + r2*256];
            }
            for (int idx = tid; idx < BB*128; idx += 256) {
                int b_ = idx >> 7, ki = idx & 127;
                vl[idx] = (ki < 64) ? sx[((size_t)b_*NN + n)*DIN + ki]
                                    : y[((size_t)b_*NN + n)*DIN + (ki - 64)];
            }
            __syncthreads();

            const int b_ = tid >> 5, op = (tid & 31) * 2;
            const unsigned* W2u = (const unsigned*)W2l4;
            float a0 = 0.f, a1 = 0.f;
            #pragma unroll 4
            for (int ki = 0; ki < 128; ++ki) {
                float vv = vl[b_*128 + ki];
                unsigned w2 = W2u[ki*32 + (op >> 1)];
                a0 += vv * __uint_as_float(w2 << 16);
                a1 += vv * __uint_as_float(w2 & 0xffff0000u);
            }
            float b0 = 0.f, b1 = 0.f;
            #pragma unroll
            for (int d = 0; d < EMB; ++d) {
                float e = El2[d];
                b0 += e * bp[d*DOUT + op];
                b1 += e * bp[d*DOUT + op + 1];
            }
            *(float2*)&out[((size_t)b_*NN + n)*DOUT + op] = make_float2(a0 + b0, a1 + b1);
        }
    }
}

extern "C" void kernel_launch(void* const* d_in, const int* in_sizes, int n_in,
                              void* d_out, int out_size, void* d_ws, size_t ws_size,
                              hipStream_t stream) {
    (void)in_sizes; (void)n_in; (void)out_size; (void)ws_size;
    const float* x  = (const float*)d_in[0];
    const float* E  = (const float*)d_in[1];
    const float* pa = (const float*)d_in[2];
    const float* wp = (const float*)d_in[3];
    const float* bp = (const float*)d_in[4];
    float* out = (float*)d_out;

    unsigned short* ws16   = (unsigned short*)d_ws;
    unsigned short* sim_bf = ws16;                       // 1,048,576 us
    unsigned short* xzT    = sim_bf + (size_t)NN*NN;     //   524,288 us
    unsigned short* sxT    = xzT + (size_t)BB*DIN*NN;    //   524,288 us
    unsigned short* Sub    = sxT + (size_t)BB*DIN*NN;    // 8,388,608 us
    unsigned short* W2     = Sub + (size_t)BB*NN*NN;     // 8,388,608 us
    float* sx = (float*)(W2 + (size_t)NN*2*DIN*DOUT);    //   524,288 f
    float* y  = sx + (size_t)BB*NN*DIN;                  //   524,288 f
    int* bars = (int*)(y + (size_t)BB*NN*DIN);           // 3 ints

    hipMemsetAsync(bars, 0, 3*sizeof(int), stream);
    k_mega<<<GRID, 256, 0, stream>>>(E, pa, x, wp, bp,
                                     sim_bf, Sub, xzT, W2, sxT, sx, y, out, bars);
}

// Round 7
// 129.344 us; speedup vs baseline: 2.7510x; 2.7510x over previous
//
#include <hip/hip_runtime.h>

#define BB 8
#define NN 1024
#define DIN 64
#define DOUT 64
#define EMB 16
#define DPC 16

typedef __attribute__((ext_vector_type(8))) short bf16x8;
typedef __attribute__((ext_vector_type(4))) float f32x4;

__device__ inline unsigned short f2bf(float f) {
    unsigned u = __float_as_uint(f);
    u += 0x7fffu + ((u >> 16) & 1u);      // RNE (finite only)
    return (unsigned short)(u >> 16);
}

#define ASTR 72
#define BSTR 72

// C[16m x 64d] = A[16m x 1024k] * B^T[64d x 1024k], K-step 64, reg prefetch.
__device__ inline void gemm_tile(const unsigned short* __restrict__ Arow,
                                 const unsigned short* __restrict__ Brow,
                                 unsigned short* A_l, unsigned short* B_l,
                                 int tid, f32x4& acc) {
    const int lane = tid & 63, wave = tid >> 6;
    const int q = lane >> 4, r = lane & 15;
    const int brow_ = tid >> 2, bch = (tid & 3) * 2;
    const int arow_ = tid >> 3, ach = tid & 7;

    uint4 pb0 = *(const uint4*)&Brow[(size_t)brow_*NN + (bch+0)*8];
    uint4 pb1 = *(const uint4*)&Brow[(size_t)brow_*NN + (bch+1)*8];
    uint4 pa0;
    if (tid < 128) pa0 = *(const uint4*)&Arow[(size_t)arow_*NN + ach*8];

    for (int kk = 0; kk < 16; ++kk) {
        __syncthreads();
        *(uint4*)&B_l[brow_*BSTR + (bch+0)*8] = pb0;
        *(uint4*)&B_l[brow_*BSTR + (bch+1)*8] = pb1;
        if (tid < 128) *(uint4*)&A_l[arow_*ASTR + ach*8] = pa0;
        __syncthreads();
        if (kk < 15) {
            int c1 = (kk + 1) * 64;
            pb0 = *(const uint4*)&Brow[(size_t)brow_*NN + c1 + (bch+0)*8];
            pb1 = *(const uint4*)&Brow[(size_t)brow_*NN + c1 + (bch+1)*8];
            if (tid < 128) pa0 = *(const uint4*)&Arow[(size_t)arow_*NN + c1 + ach*8];
        }
        bf16x8 a0 = *(const bf16x8*)&A_l[r*ASTR + q*8];
        bf16x8 b0 = *(const bf16x8*)&B_l[(wave*16 + r)*BSTR + q*8];
        acc = __builtin_amdgcn_mfma_f32_16x16x32_bf16(a0, b0, acc, 0, 0, 0);
        bf16x8 a1 = *(const bf16x8*)&A_l[r*ASTR + 32 + q*8];
        bf16x8 b1 = *(const bf16x8*)&B_l[(wave*16 + r)*BSTR + 32 + q*8];
        acc = __builtin_amdgcn_mfma_f32_16x16x32_bf16(a1, b1, acc, 0, 0, 0);
    }
}

// =======================================================================
// K1: blocks [0,512): z3 (16 c-rows) — Z, Sub, xzT.  [512,1024): sim (2 rows).
// =======================================================================
__global__ __launch_bounds__(256) void k_front(const float* __restrict__ E,
                                               const float* __restrict__ pa,
                                               const float* __restrict__ x,
                                               unsigned short* __restrict__ sim_bf,
                                               unsigned short* __restrict__ Sub,
                                               unsigned short* __restrict__ xzT) {
    __shared__ __align__(16) char smem[34816];
    const int bid = blockIdx.x, tid = threadIdx.x;
    const int lane = tid & 63, wave = tid >> 6;

    if (bid < 512) {
        const int b = bid >> 6, c0 = (bid & 63) * 16;
        float* pa_l  = (float*)smem;                 // 32 KB (reused as xl)
        float* zpart = (float*)(smem + 32768);       // 1 KB
        float* invZ  = (float*)(smem + 33792);       // 64 B

        const int cs = tid & 15, jq = tid >> 4;
        float myc[DPC];
        #pragma unroll
        for (int p4 = 0; p4 < 4; ++p4) {
            float4 t = *(const float4*)&pa[((size_t)b*NN + c0 + cs)*DPC + p4*4];
            myc[p4*4+0] = t.x; myc[p4*4+1] = t.y; myc[p4*4+2] = t.z; myc[p4*4+3] = t.w;
        }

        float part = 0.0f;
        for (int h = 0; h < 2; ++h) {
            __syncthreads();
            for (int i = tid; i < 2048; i += 256)
                ((float4*)pa_l)[i] = ((const float4*)(pa + ((size_t)b*NN + h*512)*DPC))[i];
            __syncthreads();
            unsigned short* subrow = Sub + ((size_t)b*NN + c0 + cs)*NN + h*512 + jq*32;
            for (int j8 = 0; j8 < 8; ++j8) {
                float e[4];
                #pragma unroll
                for (int t = 0; t < 4; ++t) {
                    int jj = jq*32 + j8*4 + t;
                    float s = 0.0f;
                    #pragma unroll
                    for (int p4 = 0; p4 < 4; ++p4) {
                        float4 qv = *(const float4*)&pa_l[jj*DPC + p4*4];
                        s += fabsf(myc[p4*4+0]-qv.x) + fabsf(myc[p4*4+1]-qv.y)
                           + fabsf(myc[p4*4+2]-qv.z) + fabsf(myc[p4*4+3]-qv.w);
                    }
                    e[t] = __expf(-s);
                }
                part += e[0] + e[1] + e[2] + e[3];
                *(ushort4*)&subrow[j8*4] =
                    make_ushort4(f2bf(e[0]), f2bf(e[1]), f2bf(e[2]), f2bf(e[3]));
            }
        }
        zpart[jq*16 + cs] = part;
        __syncthreads();
        float* xl = pa_l;                            // xl[16][65]
        #pragma unroll
        for (int i = 0; i < 4; ++i) {
            int l = i*256 + tid, d = l & 63, c = l >> 6;
            xl[c*65 + d] = x[((size_t)b*NN + c0 + c)*DIN + d];
        }
        if (tid < 16) {
            float z = 0.f;
            #pragma unroll
            for (int q2 = 0; q2 < 16; ++q2) z += zpart[q2*16 + tid];
            invZ[tid] = 1.0f / z;
        }
        __syncthreads();
        #pragma unroll
        for (int i = 0; i < 4; ++i) {
            int l = i*256 + tid, c = l & 15, d = l >> 4;
            xzT[((size_t)b*DIN + d)*NN + c0 + c] = f2bf(xl[c*65 + d] * invZ[c]);
        }
    } else {
        float* redw = (float*)smem;
        for (int s2 = 0; s2 < 2; ++s2) {
            const int row = (bid - 512)*2 + s2;
            __syncthreads();
            float4 ei0 = *(const float4*)&E[row*EMB + 0];
            float4 ei1 = *(const float4*)&E[row*EMB + 4];
            float4 ei2 = *(const float4*)&E[row*EMB + 8];
            float4 ei3 = *(const float4*)&E[row*EMB + 12];

            float rv[4], tmax = -1e30f;
            #pragma unroll
            for (int k = 0; k < 4; ++k) {
                int j = tid + k*256;
                float4 a0 = *(const float4*)&E[j*EMB + 0];
                float4 a1 = *(const float4*)&E[j*EMB + 4];
                float4 a2 = *(const float4*)&E[j*EMB + 8];
                float4 a3 = *(const float4*)&E[j*EMB + 12];
                float s = ei0.x*a0.x + ei0.y*a0.y + ei0.z*a0.z + ei0.w*a0.w
                        + ei1.x*a1.x + ei1.y*a1.y + ei1.z*a1.z + ei1.w*a1.w
                        + ei2.x*a2.x + ei2.y*a2.y + ei2.z*a2.z + ei2.w*a2.w
                        + ei3.x*a3.x + ei3.y*a3.y + ei3.z*a3.z + ei3.w*a3.w;
                s = fmaxf(s, 0.0f);
                rv[k] = s; tmax = fmaxf(tmax, s);
            }
            #pragma unroll
            for (int off = 32; off > 0; off >>= 1) tmax = fmaxf(tmax, __shfl_xor(tmax, off));
            if (lane == 0) redw[wave] = tmax;
            __syncthreads();
            float rmax = fmaxf(fmaxf(redw[0], redw[1]), fmaxf(redw[2], redw[3]));
            __syncthreads();

            float ev[4], tsum = 0.f;
            #pragma unroll
            for (int k = 0; k < 4; ++k) { ev[k] = __expf(rv[k] - rmax); tsum += ev[k]; }
            #pragma unroll
            for (int off = 32; off > 0; off >>= 1) tsum += __shfl_xor(tsum, off);
            if (lane == 0) redw[wave] = tsum;
            __syncthreads();
            float inv = 1.0f / (redw[0] + redw[1] + redw[2] + redw[3]);
            #pragma unroll
            for (int k = 0; k < 4; ++k)
                sim_bf[(size_t)row*NN + tid + k*256] = f2bf(ev[k] * inv);
        }
    }
}

// =======================================================================
// K2: blocks [0,512): sx-GEMM (emit sx fp32 + sxT bf16). [512,1024): wgen.
// =======================================================================
__global__ __launch_bounds__(256) void k_sxw(const unsigned short* __restrict__ Sub,
                                             const unsigned short* __restrict__ xzT,
                                             const float* __restrict__ E,
                                             const float* __restrict__ wp,
                                             float* __restrict__ sx,
                                             unsigned short* __restrict__ sxT,
                                             unsigned short* __restrict__ W2) {
    __shared__ __align__(16) char smem[11520];
    const int bid = blockIdx.x, tid = threadIdx.x;

    if (bid < 512) {
        const int b = bid >> 6, m0 = (bid & 63) * 16;
        const int lane = tid & 63, wave = tid >> 6;
        unsigned short* A_l = (unsigned short*)smem;             // 2304 B
        unsigned short* B_l = (unsigned short*)(smem + 2304);    // 9216 B
        f32x4 acc = {0.f, 0.f, 0.f, 0.f};
        gemm_tile(Sub + ((size_t)b*NN + m0)*NN, xzT + (size_t)b*DIN*NN, A_l, B_l, tid, acc);
        const int q = lane >> 4, r = lane & 15;
        const int d = wave*16 + r, mrow = m0 + q*4;
        #pragma unroll
        for (int reg = 0; reg < 4; ++reg)
            sx[((size_t)b*NN + mrow + reg)*DIN + d] = acc[reg];
        *(ushort4*)&sxT[((size_t)b*DIN + d)*NN + mrow] =
            make_ushort4(f2bf(acc[0]), f2bf(acc[1]), f2bf(acc[2]), f2bf(acc[3]));
    } else {
        const int idx = bid - 512;
        const int n0 = (idx >> 3) * 16;
        const int kio0 = (idx & 7) * 1024 + tid * 4;
        float* El = (float*)smem;                    // 16*16 f
        if (tid < 64) ((float4*)El)[tid] = ((const float4*)&E[n0*EMB])[tid];
        float4 wq[EMB];
        #pragma unroll
        for (int d = 0; d < EMB; ++d)
            wq[d] = *(const float4*)&wp[d*8192 + kio0];
        __syncthreads();
        for (int n = 0; n < 16; ++n) {
            float4 a = make_float4(0.f, 0.f, 0.f, 0.f);
            #pragma unroll
            for (int d = 0; d < EMB; ++d) {
                float e = El[n*EMB + d];
                a.x += e*wq[d].x; a.y += e*wq[d].y; a.z += e*wq[d].z; a.w += e*wq[d].w;
            }
            *(ushort4*)&W2[(size_t)(n0 + n)*8192 + kio0] =
                make_ushort4(f2bf(a.x), f2bf(a.y), f2bf(a.z), f2bf(a.w));
        }
    }
}

// =======================================================================
// K3: 512 blocks (b, n-tile16): y-GEMM (regs->LDS), then fused out for the
// same 16 nodes: out[b,n,o] = sum_ki [sx;y][ki] * W2[n,ki,o] + E[n]@bp.
// =======================================================================
__global__ __launch_bounds__(256) void k_yout(const unsigned short* __restrict__ sim_bf,
                                              const unsigned short* __restrict__ sxT,
                                              const float* __restrict__ sxin,
                                              const unsigned short* __restrict__ W2,
                                              const float* __restrict__ E,
                                              const float* __restrict__ bp,
                                              float* __restrict__ out) {
    __shared__ __align__(16) char smem[42816];
    const int bid = blockIdx.x, tid = threadIdx.x;
    const int b = bid >> 6, m0 = (bid & 63) * 16;
    const int lane = tid & 63, wave = tid >> 6;

    unsigned short* A_l = (unsigned short*)smem;               //  2304
    unsigned short* B_l = (unsigned short*)(smem + 2304);      //  9216 -> 11520
    float* yv  = (float*)(smem + 11520);                       //  16*68 f -> 15872
    float* sxv = (float*)(smem + 15872);                       //  16*68 f -> 20224
    unsigned short* W2s = (unsigned short*)(smem + 20224);     //  16384   -> 36608
    float* El  = (float*)(smem + 36608);                       //  256 f   -> 37632
    float* bpl = (float*)(smem + 37632);                       //  1024 f  -> 41728
    float* red = (float*)(smem + 41728);                       //  4*68 f  -> 42816

    // ---- phase A: y-tile GEMM ----
    f32x4 acc = {0.f, 0.f, 0.f, 0.f};
    gemm_tile(sim_bf + (size_t)m0*NN, sxT + (size_t)b*DIN*NN, A_l, B_l, tid, acc);

    const int q = lane >> 4, r = lane & 15;
    const int d = wave*16 + r;
    #pragma unroll
    for (int reg = 0; reg < 4; ++reg)
        yv[(q*4 + reg)*68 + d] = acc[reg];
    // stage sx rows, E rows, bp
    {
        int j = tid >> 4, d4 = (tid & 15) * 4;
        *(float4*)&sxv[j*68 + d4] = *(const float4*)&sxin[((size_t)b*NN + m0 + j)*DIN + d4];
    }
    El[tid] = E[m0*EMB + tid];                       // 16 nodes * 16 = 256
    ((float4*)bpl)[tid] = ((const float4*)bp)[tid];  // 1024 f = 256 float4
    __syncthreads();

    // ---- phase B: out for 16 nodes ----
    const int kq = tid >> 6;          // K quarter (32 ki each)
    const int o  = tid & 63;
    for (int nl = 0; nl < 16; ++nl) {
        // stage W2[node] : 8192 bf16 = 16 KB = 1024 uint4  (FIX: all 4 chunks)
        {
            const uint4* src = (const uint4*)(W2 + (size_t)(m0 + nl) * 8192);
            #pragma unroll
            for (int r2 = 0; r2 < 4; ++r2)
                ((uint4*)W2s)[tid + r2*256] = src[tid + r2*256];
        }
        __syncthreads();
        const float* vbase = (kq < 2) ? (sxv + nl*68 + kq*32) : (yv + nl*68 + (kq - 2)*32);
        float a = 0.f;
        #pragma unroll 8
        for (int i2 = 0; i2 < 32; ++i2) {
            int ki = kq*32 + i2;
            unsigned w = W2s[ki*64 + o];
            a += vbase[i2] * __uint_as_float(w << 16);
        }
        red[kq*68 + o] = a;
        __syncthreads();
        if (tid < 64) {
            float s = red[o] + red[68 + o] + red[136 + o] + red[204 + o];
            float bb = 0.f;
            #pragma unroll
            for (int dd = 0; dd < EMB; ++dd)
                bb += El[nl*16 + dd] * bpl[dd*64 + o];
            out[((size_t)b*NN + m0 + nl)*DOUT + o] = s + bb;
        }
        __syncthreads();
    }
}

extern "C" void kernel_launch(void* const* d_in, const int* in_sizes, int n_in,
                              void* d_out, int out_size, void* d_ws, size_t ws_size,
                              hipStream_t stream) {
    (void)in_sizes; (void)n_in; (void)out_size; (void)ws_size;
    const float* x  = (const float*)d_in[0];
    const float* E  = (const float*)d_in[1];
    const float* pa = (const float*)d_in[2];
    const float* wp = (const float*)d_in[3];
    const float* bp = (const float*)d_in[4];
    float* out = (float*)d_out;

    unsigned short* ws16   = (unsigned short*)d_ws;
    unsigned short* sim_bf = ws16;                       // 1,048,576 us
    unsigned short* xzT    = sim_bf + (size_t)NN*NN;     //   524,288 us
    unsigned short* sxT    = xzT + (size_t)BB*DIN*NN;    //   524,288 us
    unsigned short* Sub    = sxT + (size_t)BB*DIN*NN;    // 8,388,608 us
    unsigned short* W2     = Sub + (size_t)BB*NN*NN;     // 8,388,608 us
    float* sx = (float*)(W2 + (size_t)NN*2*DIN*DOUT);    //   524,288 f

    k_front<<<1024, 256, 0, stream>>>(E, pa, x, sim_bf, Sub, xzT);
    k_sxw<<<1024, 256, 0, stream>>>(Sub, xzT, E, wp, sx, sxT, W2);
    k_yout<<<512, 256, 0, stream>>>(sim_bf, sxT, sx, W2, E, bp, out);
}